// Round 4
// baseline (122.667 us; speedup 1.0000x reference)
//
#include <hip/hip_runtime.h>
#include <hip/hip_bf16.h>
#include <cmath>

// Problem constants: V=100000, E=128, B=32, S=1024, N=16
#define NS_ROWS 32768            // B*S
#define NS_NEG  16

__device__ __forceinline__ float log_sigmoid_f(float x) {
    return fminf(x, 0.0f) - log1pf(__expf(-fabsf(x)));
}

__device__ __forceinline__ float dot4(const float4 a, const float4 b) {
    return a.x * b.x + a.y * b.y + a.z * b.z + a.w * b.w;
}

// One wave per (b,s) row. 4 waves / 256-thread block, no inter-wave coupling
// until the final 4-way sum. Within a wave:
//   - context row staged to a private 512B LDS slot (same-wave dep, no barrier)
//   - pos score: coalesced 512B W-row load + 6-shuffle butterfly (from regs)
//   - 16 negs: 16 quads, each quad gathers its W row as 8 x 64B lines (8-deep
//     in flight), context re-read from LDS as quad-broadcast b128 (conflict-free)
__global__ __launch_bounds__(256) void neg_sampling_kernel(
    const int*   __restrict__ sentence,   // [ROWS]
    const float* __restrict__ context,    // [ROWS, 128]
    const int*   __restrict__ neg,        // [ROWS, 16]
    const float* __restrict__ W,          // [V, 128]
    float*       __restrict__ out)        // scalar
{
    __shared__ float cslot[4][128];       // per-wave 512B context slot
    __shared__ float wpart[4];

    const int tid  = threadIdx.x;
    const int wave = tid >> 6;
    const int lane = tid & 63;
    const int row  = (blockIdx.x << 2) + wave;   // 8192 blocks * 4 = 32768 exact
    const int q    = lane >> 2;                  // quad id 0..15 -> neg target
    const int sub  = lane & 3;

    // ---- indices ----
    const int pidx = sentence[row];                  // wave-uniform, 1 txn
    const int nidx = neg[(row << 4) + q];            // 64B per wave, 1 txn

    // ---- issue all global loads up front (max MLP) ----
    const float2 c2 = reinterpret_cast<const float2*>(context)[(row << 6) + lane];
    const float2 p2 = reinterpret_cast<const float2*>(W)[(pidx << 6) + lane];

    const float4* __restrict__ wr =
        reinterpret_cast<const float4*>(W) + (nidx << 5) + sub;
    const float4 w0 = wr[0],  w1 = wr[4],  w2 = wr[8],  w3 = wr[12];
    const float4 w4 = wr[16], w5 = wr[20], w6 = wr[24], w7 = wr[28];

    // ---- stage context into this wave's LDS slot (same-wave, lockstep) ----
    reinterpret_cast<float2*>(&cslot[wave][0])[lane] = c2;

    // ---- positive score from registers: 2 FMA + 6-shuffle butterfly ----
    float pp = c2.x * p2.x + c2.y * p2.y;
#pragma unroll
    for (int m = 32; m >= 1; m >>= 1) pp += __shfl_xor(pp, m, 64);

    // ---- negative dot: 8 x (LDS broadcast b128 + dot4), then quad butterfly ----
    const float4* cr = reinterpret_cast<const float4*>(&cslot[wave][0]);
    float acc;
    acc  = dot4(w0, cr[sub +  0]);
    acc += dot4(w1, cr[sub +  4]);
    acc += dot4(w2, cr[sub +  8]);
    acc += dot4(w3, cr[sub + 12]);
    acc += dot4(w4, cr[sub + 16]);
    acc += dot4(w5, cr[sub + 20]);
    acc += dot4(w6, cr[sub + 24]);
    acc += dot4(w7, cr[sub + 28]);
    acc += __shfl_xor(acc, 1, 64);
    acc += __shfl_xor(acc, 2, 64);

    // ---- per-lane loss, mask without divergence ----
    const float psig = log_sigmoid_f(pp);
    const float nsig = log_sigmoid_f(-acc);
    float loss = ((lane == 0) ? psig : 0.0f) + ((sub == 0) ? nsig : 0.0f);

    // ---- wave butterfly -> block 4-way -> one atomic per block ----
#pragma unroll
    for (int m = 32; m >= 1; m >>= 1) loss += __shfl_xor(loss, m, 64);

    if (lane == 0) wpart[wave] = loss;
    __syncthreads();
    if (tid == 0) {
        atomicAdd(out, -(wpart[0] + wpart[1] + wpart[2] + wpart[3]));
    }
}

extern "C" void kernel_launch(void* const* d_in, const int* in_sizes, int n_in,
                              void* d_out, int out_size, void* d_ws, size_t ws_size,
                              hipStream_t stream) {
    const int*   sentence = (const int*)d_in[0];
    const float* context  = (const float*)d_in[1];
    const int*   neg      = (const int*)d_in[2];
    const float* W        = (const float*)d_in[3];
    float*       out      = (float*)d_out;

    hipMemsetAsync(out, 0, sizeof(float), stream);

    neg_sampling_kernel<<<NS_ROWS / 4, 256, 0, stream>>>(sentence, context, neg, W, out);
}

// Round 5
// 80.014 us; speedup vs baseline: 1.5331x; 1.5331x over previous
//
#include <hip/hip_runtime.h>
#include <hip/hip_bf16.h>
#include <cmath>

// Problem constants: V=100000, E=128, B=32, S=1024, N=16
#define NS_ROWS    32768          // B*S
#define NS_NEG     16
#define NS_TARGETS 17             // 1 pos + 16 neg
#define NS_TILE    7              // rows per 512-thread block (7*17 = 119 quads of 128)
#define NS_CPAD    132            // padded context row stride in floats

__device__ __forceinline__ float log_sigmoid_f(float x) {
    return fminf(x, 0.0f) - log1pf(__expf(-fabsf(x)));
}

__device__ __forceinline__ float dot4(const float4 a, const float4 b) {
    return a.x * b.x + a.y * b.y + a.z * b.z + a.w * b.w;
}

// Round-3 structure (quads over a row-tile, one barrier) with:
//  - 512-thread blocks (8 waves, 4 blocks/CU) for fine-grained backfill
//  - explicit issue-early/consume-late: ctx-stage load + 8 gather lines all
//    issued before sched_barrier(0) + __syncthreads(); consumed after with
//    progressive vmcnt drain (no full stall point).
__global__ __launch_bounds__(512, 8) void neg_sampling_kernel(
    const int*   __restrict__ sentence,   // [ROWS]
    const float* __restrict__ context,    // [ROWS, 128]
    const int*   __restrict__ neg,        // [ROWS, 16]
    const float* __restrict__ W,          // [V, 128]
    float*       __restrict__ out)        // scalar
{
    __shared__ float cctx[NS_TILE][NS_CPAD];   // 3.7 KB
    __shared__ float wsum[8];

    const int tid     = threadIdx.x;
    const int rowbase = blockIdx.x * NS_TILE;

    // --- quad assignment: 4 lanes per (row, target) ---
    const int group = tid >> 2;               // 0..127
    const int sub   = tid & 3;
    const int lrow  = group / NS_TARGETS;     // 0..7
    const int tgt   = group - lrow * NS_TARGETS;
    const int row   = rowbase + lrow;
    const bool active = (lrow < NS_TILE) && (row < NS_ROWS);

    // --- issue context staging load (1 float4 for tids 0..223) ---
    float4 cv = make_float4(0.f, 0.f, 0.f, 0.f);
    const bool stager = (tid < NS_TILE * 32) && (rowbase + (tid >> 5) < NS_ROWS);
    if (stager) {
        cv = reinterpret_cast<const float4*>(context)[(rowbase + (tid >> 5)) * 32 + (tid & 31)];
    }

    // --- issue all 8 gather lines (64B per quad-step) ---
    float4 w0, w1, w2, w3, w4, w5, w6, w7;
    if (active) {
        const int idx = (tgt == 0) ? sentence[row] : neg[(row << 4) + (tgt - 1)];
        const float4* __restrict__ wr =
            reinterpret_cast<const float4*>(W) + (size_t)idx * 32 + sub;
        w0 = wr[0];  w1 = wr[4];  w2 = wr[8];  w3 = wr[12];
        w4 = wr[16]; w5 = wr[20]; w6 = wr[24]; w7 = wr[28];
    } else {
        w0=w1=w2=w3=w4=w5=w6=w7 = make_float4(0.f,0.f,0.f,0.f);
    }

    // Pin: everything above is ISSUED before anything below executes.
    __builtin_amdgcn_sched_barrier(0);

    // --- stage context to LDS (waits only on cv: vmcnt leaves gathers in flight) ---
    if (stager) {
        *reinterpret_cast<float4*>(&cctx[tid >> 5][(tid & 31) * 4]) = cv;
    }
    __syncthreads();

    // --- consume: 8 x (LDS broadcast b128 + dot4), progressive vmcnt drain ---
    float loss = 0.0f;
    if (active) {
        const float4* cr = reinterpret_cast<const float4*>(&cctx[lrow][0]);
        float acc;
        acc  = dot4(w0, cr[sub +  0]);
        acc += dot4(w1, cr[sub +  4]);
        acc += dot4(w2, cr[sub +  8]);
        acc += dot4(w3, cr[sub + 12]);
        acc += dot4(w4, cr[sub + 16]);
        acc += dot4(w5, cr[sub + 20]);
        acc += dot4(w6, cr[sub + 24]);
        acc += dot4(w7, cr[sub + 28]);
        acc += __shfl_xor(acc, 1, 64);
        acc += __shfl_xor(acc, 2, 64);
        if (sub == 0) {
            loss = log_sigmoid_f((tgt == 0) ? acc : -acc);
        }
    }

    // --- wave butterfly -> 8-way block reduce -> one atomic per block ---
#pragma unroll
    for (int m = 32; m >= 1; m >>= 1) loss += __shfl_xor(loss, m, 64);

    const int wave = tid >> 6, lane = tid & 63;
    if (lane == 0) wsum[wave] = loss;
    __syncthreads();
    if (tid == 0) {
        float t = 0.0f;
#pragma unroll
        for (int i = 0; i < 8; ++i) t += wsum[i];
        atomicAdd(out, -t);
    }
}

extern "C" void kernel_launch(void* const* d_in, const int* in_sizes, int n_in,
                              void* d_out, int out_size, void* d_ws, size_t ws_size,
                              hipStream_t stream) {
    const int*   sentence = (const int*)d_in[0];
    const float* context  = (const float*)d_in[1];
    const int*   neg      = (const int*)d_in[2];
    const float* W        = (const float*)d_in[3];
    float*       out      = (float*)d_out;

    hipMemsetAsync(out, 0, sizeof(float), stream);

    const int blocks = (NS_ROWS + NS_TILE - 1) / NS_TILE;  // 4682
    neg_sampling_kernel<<<blocks, 512, 0, stream>>>(sentence, context, neg, W, out);
}